// Round 6
// baseline (343.077 us; speedup 1.0000x reference)
//
#include <hip/hip_runtime.h>
#include <math.h>

// ExpertGate: scores = sigmoid(X @ W^T); top-8 with bias-for-selection, gather
// un-biased scores, renormalize * 2.5. Out: weights fp32 (N*8), then indices-as-float.
//
// R6: fp32 VALU, MFMA abandoned. R3/R4/R5 (three different split-bf16 numerics)
// failed with IDENTICAL absmax=35 -> flips come from the MFMA instruction's
// internal hh-term rounding (shared bit-for-bit across all three), ~1e-6 logit,
// right at the rank-8/9 gap floor. Not fixable at source level.
//
// Structure: lane = token (64 tok/wave); 8 waves x 8 experts; W operand is
// wave-uniform -> readfirstlane'd base -> s_load (scalar pipe); X streamed
// per-lane via float4 (64B lines fully consumed across 4 k-steps, L1-hot).
// NO LDS, NO barriers in the K-loop (R1 was ds_read-pipe-bound at 186 us).
// Accumulation: fmaf over k strictly ascending, x/y/z/w order == R1's chain
// bitwise -> R1 passed with exact indices, so this passes.

#define D_DIM 2048
#define E_DIM 64
#define TOPK 8
#define TM 64          // tokens per block (= lanes per wave)
#define EW 8           // experts per wave (8 waves x 8 = 64)

__global__ __launch_bounds__(512) void expert_gate_kernel(
    const float* __restrict__ x,      // (N, 2048)
    const float* __restrict__ w,      // (64, 2048)
    const float* __restrict__ bias,   // (64,)
    float* __restrict__ out,          // N*8 weights, then N*8 indices-as-float
    int N)
{
    __shared__ float Sc[TM][65];      // scores for top-k (65: conflict-free cols)

    const int t    = threadIdx.x;
    const int wv   = t >> 6;          // 0..7: this wave's expert group
    const int lane = t & 63;          // this lane's token within the block
    const int tok0 = blockIdx.x * TM;

    // Uniform W base for this wave's 8 experts: readfirstlane makes it SGPR,
    // so the float4 W reads below compile to s_load (scalar pipe, not VALU).
    const int wv_u = __builtin_amdgcn_readfirstlane(wv);
    const float* __restrict__ wbase = w + (size_t)(wv_u * EW) * D_DIM;

    // Per-lane X row (this lane's token).
    const float* __restrict__ xrow = x + (size_t)(tok0 + lane) * D_DIM;

    float acc[EW] = {0.f, 0.f, 0.f, 0.f, 0.f, 0.f, 0.f, 0.f};

    // one-deep prefetch of the per-lane X float4
    float4 xv_n = *(const float4*)(xrow);

    for (int k = 0; k < D_DIM; k += 4) {
        const float4 xv = xv_n;
        if (k + 4 < D_DIM) xv_n = *(const float4*)(xrow + k + 4);

        #pragma unroll
        for (int e = 0; e < EW; ++e) {
            const float4 b = *(const float4*)(wbase + (size_t)e * D_DIM + k);
            // strict k-ascending, x/y/z/w order: bitwise == R1's passing chain
            acc[e] = fmaf(xv.x, b.x, acc[e]);
            acc[e] = fmaf(xv.y, b.y, acc[e]);
            acc[e] = fmaf(xv.z, b.z, acc[e]);
            acc[e] = fmaf(xv.w, b.w, acc[e]);
        }
    }

    // sigmoid, park scores: Sc[token][expert]
    #pragma unroll
    for (int e = 0; e < EW; ++e) {
        const float s = 1.0f / (1.0f + expf(-acc[e]));
        Sc[lane][wv * EW + e] = s;
    }
    __syncthreads();

    // ---- top-8 per token: lane == expert; each wave handles 8 tokens ----
    const float my_bias = bias[lane];
    for (int r = 0; r < 8; ++r) {
        const int tok = wv * 8 + r;
        const float s = Sc[tok][lane];   // original score
        float rv = s + my_bias;          // routing score
        float outw = 0.f;
        int   outi = 0;
        float ssum = 0.f;
        #pragma unroll
        for (int sel = 0; sel < TOPK; ++sel) {
            float v = rv;
            int   vi = lane;
            #pragma unroll
            for (int off = 1; off < 64; off <<= 1) {   // lexicographic max
                float ov = __shfl_xor(v, off);
                int   oi = __shfl_xor(vi, off);
                if (ov > v || (ov == v && oi < vi)) { v = ov; vi = oi; }
            }
            float cs = __shfl(s, vi);    // un-biased score of winner
            ssum += cs;
            if (lane == sel) { outw = cs; outi = vi; }
            if (lane == vi) rv = -INFINITY;
        }
        if (lane < TOPK) {
            const size_t base = (size_t)(tok0 + tok) * TOPK + lane;
            out[base] = outw / (ssum + 1e-8f) * 2.5f;
            out[(size_t)N * TOPK + base] = (float)outi;
        }
    }
}

extern "C" void kernel_launch(void* const* d_in, const int* in_sizes, int n_in,
                              void* d_out, int out_size, void* d_ws, size_t ws_size,
                              hipStream_t stream) {
    const float* x    = (const float*)d_in[0];
    const float* w    = (const float*)d_in[1];
    const float* bias = (const float*)d_in[2];
    float* out = (float*)d_out;
    const int N = in_sizes[0] / D_DIM;  // 16384
    const int grid = N / TM;            // 256 blocks of 512 thr = 8 waves/CU
    expert_gate_kernel<<<grid, 512, 0, stream>>>(x, w, bias, out, N);
}